// Round 1
// 1861.552 us; speedup vs baseline: 1.0741x; 1.0741x over previous
//
#include <hip/hip_runtime.h>
#include <math.h>

#define HID 64
#define TST 2048
#define CH 16              // timesteps per chunk
#define NCH (TST / CH)     // 128 chunks
#define EPSN 1e-5f

typedef float v2f __attribute__((ext_vector_type(2)));

// ---------------------------------------------------------------------------
// Kernel 1: x = GELU(LayerNorm(ce @ w1 + b1))  -> staged into d_out
// ---------------------------------------------------------------------------
__global__ void k_inproj(const float* __restrict__ ce, const float* __restrict__ w1,
                         const float* __restrict__ b1, const float* __restrict__ g1,
                         const float* __restrict__ be1, float* __restrict__ xout,
                         int nrows) {
    const int lane = threadIdx.x & 63;
    const int wave = threadIdx.x >> 6;
    const long row = (long)blockIdx.x * 4 + wave;
    if (row >= nrows) return;
    const float* cr = ce + row * 6;
    float acc = b1[lane];
    acc += cr[0] * w1[0 * HID + lane];
    acc += cr[1] * w1[1 * HID + lane];
    acc += cr[2] * w1[2 * HID + lane];
    acc += cr[3] * w1[3 * HID + lane];
    acc += cr[4] * w1[4 * HID + lane];
    acc += cr[5] * w1[5 * HID + lane];
    float s = acc;
#pragma unroll
    for (int m = 32; m >= 1; m >>= 1) s += __shfl_xor(s, m, 64);
    const float mean = s * (1.0f / 64.0f);
    const float d = acc - mean;
    float q = d * d;
#pragma unroll
    for (int m = 32; m >= 1; m >>= 1) q += __shfl_xor(q, m, 64);
    const float var = q * (1.0f / 64.0f);
    const float xn = d * rsqrtf(var + EPSN) * g1[lane] + be1[lane];
    const float ge = 0.5f * xn * (1.0f + erff(xn * 0.70710678118654752440f));
    xout[row * HID + lane] = ge;
}

// ---------------------------------------------------------------------------
// Kernel 2: GRU scan, wave-specialized, chunk-phased.
//   wave 0: serial scan, h via LDS broadcast, no barriers inside a chunk.
//   waves 1-2: gi = W_ih.x + b_ih for chunk p (one ahead), double-buffered.
//   wave 3: LN(h@w2+b2) epilogue for chunk p-2, then x prefetch for p+1.
//
// KEY CHANGE vs previous version: all per-wave weight arrays live in ONE
// unioned register array W[96] (192 VGPRs). Previously wr/wz/wn (192) +
// wiA/wiB (128) + w2v (64) + yv/sv/qv (48) were simultaneously live from
// the allocator's view -> ~430 VGPRs of pressure -> ~200 regs spilled to
// scratch, reloaded every t-loop iteration on the critical scan wave.
// The union removes the false pressure; total fits in 256 with no spills.
// ---------------------------------------------------------------------------
__global__ __launch_bounds__(256, 1)
__attribute__((amdgpu_waves_per_eu(1, 1)))
void k_gru(float* xo,
           const float* __restrict__ W_ih, const float* __restrict__ b_ih,
           const float* __restrict__ W_hh, const float* __restrict__ b_hh,
           const float* __restrict__ w2, const float* __restrict__ b2,
           const float* __restrict__ g2, const float* __restrict__ be2) {
    __shared__ __align__(16) float4 xbuf[2][CH][16];    // 8 KB  x chunks
    __shared__ __align__(16) float gibuf[2][CH][192];   // 24 KB gi preacts
    __shared__ __align__(16) float hist[2][CH][HID];    // 8 KB  h history
    __shared__ __align__(16) float hbuf[HID];           // h broadcast (wave 0)

    const int tid = threadIdx.x;
    const int lane = tid & 63;
    const int wv = tid >> 6;
    float* xb = xo + (size_t)blockIdx.x * TST * HID;

    // Unioned weight register file (192 VGPRs), contents per wave:
    //   wave 0: W[0:31]=W_hh r-rows, W[32:63]=z-rows, W[64:95]=n-rows
    //   wave 1: W[0:31]=W_ih r-rows, W[32:63]=W_ih n-rows
    //   wave 2: W[0:31]=W_ih z-rows
    //   wave 3: W[0:31]=w2 column (lane's output dim)
    v2f W[96];
    float sc0 = 0.f, sc1 = 0.f, sc2 = 0.f;   // per-wave scalar params

    if (wv == 0) {
        const v2f* r0 = (const v2f*)(W_hh + (size_t)lane * HID);
        const v2f* r1 = (const v2f*)(W_hh + (size_t)(64 + lane) * HID);
        const v2f* r2 = (const v2f*)(W_hh + (size_t)(128 + lane) * HID);
#pragma unroll
        for (int k = 0; k < 32; ++k) { W[k] = r0[k]; W[32 + k] = r1[k]; W[64 + k] = r2[k]; }
        sc0 = b_hh[lane]; sc1 = b_hh[64 + lane]; sc2 = b_hh[128 + lane];
        hbuf[lane] = 0.0f;
    } else if (wv == 1) {
        const v2f* rA = (const v2f*)(W_ih + (size_t)lane * HID);
        const v2f* rB = (const v2f*)(W_ih + (size_t)(128 + lane) * HID);
#pragma unroll
        for (int k = 0; k < 32; ++k) { W[k] = rA[k]; W[32 + k] = rB[k]; }
        sc0 = b_ih[lane]; sc1 = b_ih[128 + lane];
    } else if (wv == 2) {
        const v2f* rA = (const v2f*)(W_ih + (size_t)(64 + lane) * HID);
#pragma unroll
        for (int k = 0; k < 32; ++k) { W[k] = rA[k]; }
        sc0 = b_ih[64 + lane];
    } else {
#pragma unroll
        for (int k = 0; k < 32; ++k) {
            W[k].x = w2[(size_t)(2 * k) * HID + lane];
            W[k].y = w2[(size_t)(2 * k + 1) * HID + lane];
        }
        sc0 = b2[lane]; sc1 = g2[lane]; sc2 = be2[lane];
    }

    {
        const float4* src = (const float4*)xb;
        ((float4*)xbuf[0])[tid] = src[tid];
    }
    float h_reg = 0.0f;
    __syncthreads();

    for (int p = 0; p <= NCH + 1; ++p) {
        if (wv == 0) {
            if (p >= 1 && p <= NCH) {
                const int c = p - 1;
                const float* gp = (const float*)gibuf[c & 1];
                float* hp = (float*)hist[c & 1];
                for (int t = 0; t < CH; ++t) {
                    const float gr = gp[t * 192 + lane];
                    const float gz = gp[t * 192 + 64 + lane];
                    const float gn = gp[t * 192 + 128 + lane];
                    const v2f* hv = (const v2f*)hbuf;
                    // 2-way split accumulators: halve the dependent FMA chain
                    v2f ar0 = {0.f, 0.f}, ar1 = {0.f, 0.f};
                    v2f az0 = {0.f, 0.f}, az1 = {0.f, 0.f};
                    v2f an0 = {0.f, 0.f}, an1 = {0.f, 0.f};
#pragma unroll
                    for (int k = 0; k < 32; k += 2) {
                        const v2f h2a = hv[k];
                        const v2f h2b = hv[k + 1];
                        ar0 += W[k] * h2a;       ar1 += W[k + 1] * h2b;
                        az0 += W[32 + k] * h2a;  az1 += W[32 + k + 1] * h2b;
                        an0 += W[64 + k] * h2a;  an1 += W[64 + k + 1] * h2b;
                    }
                    const v2f arv = ar0 + ar1;
                    const v2f azv = az0 + az1;
                    const v2f anv = an0 + an1;
                    const float rpre = gr + arv.x + arv.y + sc0;
                    const float zpre = gz + azv.x + azv.y + sc1;
                    const float hn = anv.x + anv.y + sc2;
                    const float r = 1.0f / (1.0f + __expf(-rpre));
                    const float z = 1.0f / (1.0f + __expf(-zpre));
                    const float pre = gn + r * hn;
                    const float e2 = __expf(2.0f * pre);
                    const float n = 1.0f - 2.0f / (e2 + 1.0f);
                    h_reg = (1.0f - z) * n + z * h_reg;
                    hbuf[lane] = h_reg;
                    hp[t * HID + lane] = h_reg;
                }
            }
        } else if (wv == 1 || wv == 2) {
            if (p < NCH) {
                const float4* xc = (const float4*)xbuf[p & 1];
                float* gp = (float*)gibuf[p & 1];
                for (int t = 0; t < CH; ++t) {
                    const v2f* xv = (const v2f*)(xc + t * 16);
                    v2f aA = {0.f, 0.f}, aB = {0.f, 0.f};
                    if (wv == 1) {
#pragma unroll
                        for (int k = 0; k < 32; ++k) {
                            const v2f x2 = xv[k];
                            aA += W[k] * x2;
                            aB += W[32 + k] * x2;
                        }
                        gp[t * 192 + lane] = aA.x + aA.y + sc0;
                        gp[t * 192 + 128 + lane] = aB.x + aB.y + sc1;
                    } else {
#pragma unroll
                        for (int k = 0; k < 32; ++k) {
                            const v2f x2 = xv[k];
                            aA += W[k] * x2;
                        }
                        gp[t * 192 + 64 + lane] = aA.x + aA.y + sc0;
                    }
                }
            }
        } else {
            // ---- epilogue for chunk p-2: LN over 16 timesteps, 2 halves of 8
            //      (halves live temporaries: 24 floats instead of 48) ----
            if (p >= 2) {
                const int ce = p - 2;
                const float* hp = (const float*)hist[ce & 1];
#pragma unroll
                for (int half = 0; half < 2; ++half) {
                    float yv[8], sv[8], qv[8];
#pragma unroll
                    for (int u = 0; u < 8; ++u) {
                        const int t = half * 8 + u;
                        const v2f* hr = (const v2f*)(hp + t * HID);
                        v2f a2 = {0.f, 0.f};
#pragma unroll
                        for (int k = 0; k < 32; ++k) a2 += W[k] * hr[k];
                        yv[u] = sc0 + a2.x + a2.y;
                    }
#pragma unroll
                    for (int u = 0; u < 8; ++u) { sv[u] = yv[u]; qv[u] = yv[u] * yv[u]; }
                    // 16 independent shuffle streams per level -> latency overlaps
#pragma unroll
                    for (int m = 32; m >= 1; m >>= 1) {
#pragma unroll
                        for (int u = 0; u < 8; ++u) sv[u] += __shfl_xor(sv[u], m, 64);
#pragma unroll
                        for (int u = 0; u < 8; ++u) qv[u] += __shfl_xor(qv[u], m, 64);
                    }
#pragma unroll
                    for (int u = 0; u < 8; ++u) {
                        const int t = half * 8 + u;
                        const float mean = sv[u] * (1.0f / 64.0f);
                        const float var = qv[u] * (1.0f / 64.0f) - mean * mean;
                        const float dd = yv[u] - mean;
                        xb[(size_t)(ce * CH + t) * HID + lane] =
                            dd * rsqrtf(var + EPSN) * sc1 + sc2;
                    }
                }
            }
            // prefetch x chunk p+1
            if (p + 1 < NCH) {
                const float4* src = (const float4*)(xb + (size_t)(p + 1) * CH * HID);
                float4* dst = (float4*)xbuf[(p + 1) & 1];
#pragma unroll
                for (int q2 = 0; q2 < 4; ++q2) dst[lane + q2 * 64] = src[lane + q2 * 64];
            }
        }
        __syncthreads();
    }
}

extern "C" void kernel_launch(void* const* d_in, const int* in_sizes, int n_in,
                              void* d_out, int out_size, void* d_ws, size_t ws_size,
                              hipStream_t stream) {
    const float* ce  = (const float*)d_in[0];
    const float* w1  = (const float*)d_in[1];
    const float* b1  = (const float*)d_in[2];
    const float* g1  = (const float*)d_in[3];
    const float* be1 = (const float*)d_in[4];
    const float* Wih = (const float*)d_in[5];
    const float* bih = (const float*)d_in[6];
    const float* Whh = (const float*)d_in[7];
    const float* bhh = (const float*)d_in[8];
    const float* w2  = (const float*)d_in[9];
    const float* b2  = (const float*)d_in[10];
    const float* g2  = (const float*)d_in[11];
    const float* be2 = (const float*)d_in[12];
    float* out = (float*)d_out;

    const int nrows = in_sizes[0] / 6;   // B*T
    const int B = nrows / TST;           // 256

    k_inproj<<<(nrows + 3) / 4, 256, 0, stream>>>(ce, w1, b1, g1, be1, out, nrows);
    k_gru<<<B, 256, 0, stream>>>(out, Wih, bih, Whh, bhh, w2, b2, g2, be2);
}

// Round 2
// 1807.655 us; speedup vs baseline: 1.1062x; 1.0298x over previous
//
#include <hip/hip_runtime.h>
#include <math.h>

#define HID 64
#define TST 2048
#define CH 16              // timesteps per chunk
#define NCH (TST / CH)     // 128 chunks
#define EPSN 1e-5f

typedef float v2f __attribute__((ext_vector_type(2)));

#define REP32(M) M(0) M(1) M(2) M(3) M(4) M(5) M(6) M(7) \
                 M(8) M(9) M(10) M(11) M(12) M(13) M(14) M(15) \
                 M(16) M(17) M(18) M(19) M(20) M(21) M(22) M(23) \
                 M(24) M(25) M(26) M(27) M(28) M(29) M(30) M(31)

// ---------------------------------------------------------------------------
// Kernel 1: x = GELU(LayerNorm(ce @ w1 + b1))  -> staged into d_out
// ---------------------------------------------------------------------------
__global__ void k_inproj(const float* __restrict__ ce, const float* __restrict__ w1,
                         const float* __restrict__ b1, const float* __restrict__ g1,
                         const float* __restrict__ be1, float* __restrict__ xout,
                         int nrows) {
    const int lane = threadIdx.x & 63;
    const int wave = threadIdx.x >> 6;
    const long row = (long)blockIdx.x * 4 + wave;
    if (row >= nrows) return;
    const float* cr = ce + row * 6;
    float acc = b1[lane];
    acc += cr[0] * w1[0 * HID + lane];
    acc += cr[1] * w1[1 * HID + lane];
    acc += cr[2] * w1[2 * HID + lane];
    acc += cr[3] * w1[3 * HID + lane];
    acc += cr[4] * w1[4 * HID + lane];
    acc += cr[5] * w1[5 * HID + lane];
    float s = acc;
#pragma unroll
    for (int m = 32; m >= 1; m >>= 1) s += __shfl_xor(s, m, 64);
    const float mean = s * (1.0f / 64.0f);
    const float d = acc - mean;
    float q = d * d;
#pragma unroll
    for (int m = 32; m >= 1; m >>= 1) q += __shfl_xor(q, m, 64);
    const float var = q * (1.0f / 64.0f);
    const float xn = d * rsqrtf(var + EPSN) * g1[lane] + be1[lane];
    const float ge = 0.5f * xn * (1.0f + erff(xn * 0.70710678118654752440f));
    xout[row * HID + lane] = ge;
}

// ---------------------------------------------------------------------------
// Kernel 2: GRU scan, wave-specialized, chunk-phased.
//   wave 0: serial scan, h via LDS broadcast.
//   waves 1-2: gi = W_ih.x + b_ih for chunk p (one ahead), double-buffered.
//   wave 3: LN(h@w2+b2) epilogue for chunk p-2, then x prefetch for p+1.
//
// KEY CHANGE vs previous version: the unioned v2f W[96] array was DEMOTED by
// the compiler (VGPR_Count=132 < the 192 regs W needs -> W lived in scratch,
// reloaded every timestep on the critical scan wave; ~1980 cy/step measured
// vs ~550 cy issue model). Arrays initialized+consumed under divergent
// branches are exactly what LLVM demotes. Fix: 96 individually-NAMED v2f
// variables (A0..A31, B0..B31, C0..C31) with fully macro-expanded loops —
// named scalars SROA into independent SSA values the allocator keeps in
// VGPRs (peak pressure ~230 < 256, no spill expected).
//   wave 0: A=W_hh r-rows, B=z-rows, C=n-rows
//   wave 1: A=W_ih r-rows, B=W_ih n-rows
//   wave 2: A=W_ih z-rows
//   wave 3: A=w2 column (lane's output dim)
// ---------------------------------------------------------------------------
__global__ __launch_bounds__(256, 1)
__attribute__((amdgpu_waves_per_eu(1, 1)))
void k_gru(float* xo,
           const float* __restrict__ W_ih, const float* __restrict__ b_ih,
           const float* __restrict__ W_hh, const float* __restrict__ b_hh,
           const float* __restrict__ w2, const float* __restrict__ b2,
           const float* __restrict__ g2, const float* __restrict__ be2) {
    __shared__ __align__(16) float4 xbuf[2][CH][16];    // 8 KB  x chunks
    __shared__ __align__(16) float gibuf[2][CH][192];   // 24 KB gi preacts
    __shared__ __align__(16) float hist[2][CH][HID];    // 8 KB  h history
    __shared__ __align__(16) float hbuf[HID];           // h broadcast (wave 0)

    const int tid = threadIdx.x;
    const int lane = tid & 63;
    const int wv = tid >> 6;
    float* xb = xo + (size_t)blockIdx.x * TST * HID;

#define DECLW(i) v2f A##i, B##i, C##i;
    REP32(DECLW)
    float sc0 = 0.f, sc1 = 0.f, sc2 = 0.f;   // per-wave scalar params

    if (wv == 0) {
        const v2f* r0 = (const v2f*)(W_hh + (size_t)lane * HID);
        const v2f* r1 = (const v2f*)(W_hh + (size_t)(64 + lane) * HID);
        const v2f* r2 = (const v2f*)(W_hh + (size_t)(128 + lane) * HID);
#define LW0(i) A##i = r0[i]; B##i = r1[i]; C##i = r2[i];
        REP32(LW0)
        sc0 = b_hh[lane]; sc1 = b_hh[64 + lane]; sc2 = b_hh[128 + lane];
        hbuf[lane] = 0.0f;
    } else if (wv == 1) {
        const v2f* rA = (const v2f*)(W_ih + (size_t)lane * HID);
        const v2f* rB = (const v2f*)(W_ih + (size_t)(128 + lane) * HID);
#define LW1(i) A##i = rA[i]; B##i = rB[i];
        REP32(LW1)
        sc0 = b_ih[lane]; sc1 = b_ih[128 + lane];
    } else if (wv == 2) {
        const v2f* rC = (const v2f*)(W_ih + (size_t)(64 + lane) * HID);
#define LW2(i) A##i = rC[i];
        REP32(LW2)
        sc0 = b_ih[64 + lane];
    } else {
#define LW3(i) A##i.x = w2[(size_t)(2 * (i)) * HID + lane]; \
               A##i.y = w2[(size_t)(2 * (i) + 1) * HID + lane];
        REP32(LW3)
        sc0 = b2[lane]; sc1 = g2[lane]; sc2 = be2[lane];
    }

    {
        const float4* src = (const float4*)xb;
        ((float4*)xbuf[0])[tid] = src[tid];
    }
    float h_reg = 0.0f;
    __syncthreads();

    for (int p = 0; p <= NCH + 1; ++p) {
        if (wv == 0) {
            if (p >= 1 && p <= NCH) {
                const int c = p - 1;
                const float* gp = (const float*)gibuf[c & 1];
                float* hp = (float*)hist[c & 1];
                for (int t = 0; t < CH; ++t) {
                    const float gr = gp[t * 192 + lane];
                    const float gz = gp[t * 192 + 64 + lane];
                    const float gn = gp[t * 192 + 128 + lane];
                    const v2f* hv = (const v2f*)hbuf;
                    // 2-way split accumulators: halve the dependent FMA chain
                    v2f ar0 = {0.f, 0.f}, ar1 = {0.f, 0.f};
                    v2f az0 = {0.f, 0.f}, az1 = {0.f, 0.f};
                    v2f an0 = {0.f, 0.f}, an1 = {0.f, 0.f};
#define SFMA(i) { const v2f h2 = hv[i]; \
                  if ((i) & 1) { ar1 += A##i * h2; az1 += B##i * h2; an1 += C##i * h2; } \
                  else         { ar0 += A##i * h2; az0 += B##i * h2; an0 += C##i * h2; } }
                    REP32(SFMA)
                    const v2f arv = ar0 + ar1;
                    const v2f azv = az0 + az1;
                    const v2f anv = an0 + an1;
                    const float rpre = gr + arv.x + arv.y + sc0;
                    const float zpre = gz + azv.x + azv.y + sc1;
                    const float hn = anv.x + anv.y + sc2;
                    const float r = 1.0f / (1.0f + __expf(-rpre));
                    const float z = 1.0f / (1.0f + __expf(-zpre));
                    const float pre = gn + r * hn;
                    const float e2 = __expf(2.0f * pre);
                    const float n = 1.0f - 2.0f / (e2 + 1.0f);
                    h_reg = (1.0f - z) * n + z * h_reg;
                    hbuf[lane] = h_reg;
                    hp[t * HID + lane] = h_reg;
                }
            }
        } else if (wv == 1 || wv == 2) {
            if (p < NCH) {
                const float4* xc = (const float4*)xbuf[p & 1];
                float* gp = (float*)gibuf[p & 1];
                for (int t = 0; t < CH; ++t) {
                    const v2f* xv = (const v2f*)(xc + t * 16);
                    v2f aA0 = {0.f, 0.f}, aA1 = {0.f, 0.f};
                    v2f aB0 = {0.f, 0.f}, aB1 = {0.f, 0.f};
                    if (wv == 1) {
#define GFMA1(i) { const v2f x2 = xv[i]; \
                   if ((i) & 1) { aA1 += A##i * x2; aB1 += B##i * x2; } \
                   else         { aA0 += A##i * x2; aB0 += B##i * x2; } }
                        REP32(GFMA1)
                        gp[t * 192 + lane] = aA0.x + aA0.y + aA1.x + aA1.y + sc0;
                        gp[t * 192 + 128 + lane] = aB0.x + aB0.y + aB1.x + aB1.y + sc1;
                    } else {
#define GFMA2(i) { const v2f x2 = xv[i]; \
                   if ((i) & 1) { aA1 += A##i * x2; } \
                   else         { aA0 += A##i * x2; } }
                        REP32(GFMA2)
                        gp[t * 192 + 64 + lane] = aA0.x + aA0.y + aA1.x + aA1.y + sc0;
                    }
                }
            }
        } else {
            // ---- epilogue for chunk p-2: LN over 16 timesteps, 2 halves of 8 ----
            if (p >= 2) {
                const int ce = p - 2;
                const float* hp = (const float*)hist[ce & 1];
#pragma unroll
                for (int half = 0; half < 2; ++half) {
                    float yv[8], sv[8], qv[8];
#pragma unroll
                    for (int u = 0; u < 8; ++u) {
                        const int t = half * 8 + u;
                        const v2f* hr = (const v2f*)(hp + t * HID);
                        v2f a20 = {0.f, 0.f}, a21 = {0.f, 0.f};
#define EFMA(i) { const v2f h2 = hr[i]; \
                  if ((i) & 1) { a21 += A##i * h2; } else { a20 += A##i * h2; } }
                        REP32(EFMA)
                        yv[u] = sc0 + a20.x + a20.y + a21.x + a21.y;
                    }
#pragma unroll
                    for (int u = 0; u < 8; ++u) { sv[u] = yv[u]; qv[u] = yv[u] * yv[u]; }
                    // 16 independent shuffle streams per level -> latency overlaps
#pragma unroll
                    for (int m = 32; m >= 1; m >>= 1) {
#pragma unroll
                        for (int u = 0; u < 8; ++u) sv[u] += __shfl_xor(sv[u], m, 64);
#pragma unroll
                        for (int u = 0; u < 8; ++u) qv[u] += __shfl_xor(qv[u], m, 64);
                    }
#pragma unroll
                    for (int u = 0; u < 8; ++u) {
                        const int t = half * 8 + u;
                        const float mean = sv[u] * (1.0f / 64.0f);
                        const float var = qv[u] * (1.0f / 64.0f) - mean * mean;
                        const float dd = yv[u] - mean;
                        xb[(size_t)(ce * CH + t) * HID + lane] =
                            dd * rsqrtf(var + EPSN) * sc1 + sc2;
                    }
                }
            }
            // prefetch x chunk p+1
            if (p + 1 < NCH) {
                const float4* src = (const float4*)(xb + (size_t)(p + 1) * CH * HID);
                float4* dst = (float4*)xbuf[(p + 1) & 1];
#pragma unroll
                for (int q2 = 0; q2 < 4; ++q2) dst[lane + q2 * 64] = src[lane + q2 * 64];
            }
        }
        __syncthreads();
    }
}

extern "C" void kernel_launch(void* const* d_in, const int* in_sizes, int n_in,
                              void* d_out, int out_size, void* d_ws, size_t ws_size,
                              hipStream_t stream) {
    const float* ce  = (const float*)d_in[0];
    const float* w1  = (const float*)d_in[1];
    const float* b1  = (const float*)d_in[2];
    const float* g1  = (const float*)d_in[3];
    const float* be1 = (const float*)d_in[4];
    const float* Wih = (const float*)d_in[5];
    const float* bih = (const float*)d_in[6];
    const float* Whh = (const float*)d_in[7];
    const float* bhh = (const float*)d_in[8];
    const float* w2  = (const float*)d_in[9];
    const float* b2  = (const float*)d_in[10];
    const float* g2  = (const float*)d_in[11];
    const float* be2 = (const float*)d_in[12];
    float* out = (float*)d_out;

    const int nrows = in_sizes[0] / 6;   // B*T
    const int B = nrows / TST;           // 256

    k_inproj<<<(nrows + 3) / 4, 256, 0, stream>>>(ce, w1, b1, g1, be1, out, nrows);
    k_gru<<<B, 256, 0, stream>>>(out, Wih, bih, Whh, bhh, w2, b2, g2, be2);
}

// Round 3
// 1802.204 us; speedup vs baseline: 1.1095x; 1.0030x over previous
//
#include <hip/hip_runtime.h>
#include <math.h>

#define HID 64
#define TST 2048
#define CH 16              // timesteps per chunk
#define NCH (TST / CH)     // 128 chunks
#define EPSN 1e-5f

typedef float v2f __attribute__((ext_vector_type(2)));

#define REP32(M) M(0) M(1) M(2) M(3) M(4) M(5) M(6) M(7) \
                 M(8) M(9) M(10) M(11) M(12) M(13) M(14) M(15) \
                 M(16) M(17) M(18) M(19) M(20) M(21) M(22) M(23) \
                 M(24) M(25) M(26) M(27) M(28) M(29) M(30) M(31)

// ---------------------------------------------------------------------------
// Kernel 1: x = GELU(LayerNorm(ce @ w1 + b1))  -> staged into d_out
// ---------------------------------------------------------------------------
__global__ void k_inproj(const float* __restrict__ ce, const float* __restrict__ w1,
                         const float* __restrict__ b1, const float* __restrict__ g1,
                         const float* __restrict__ be1, float* __restrict__ xout,
                         int nrows) {
    const int lane = threadIdx.x & 63;
    const int wave = threadIdx.x >> 6;
    const long row = (long)blockIdx.x * 4 + wave;
    if (row >= nrows) return;
    const float* cr = ce + row * 6;
    float acc = b1[lane];
    acc += cr[0] * w1[0 * HID + lane];
    acc += cr[1] * w1[1 * HID + lane];
    acc += cr[2] * w1[2 * HID + lane];
    acc += cr[3] * w1[3 * HID + lane];
    acc += cr[4] * w1[4 * HID + lane];
    acc += cr[5] * w1[5 * HID + lane];
    float s = acc;
#pragma unroll
    for (int m = 32; m >= 1; m >>= 1) s += __shfl_xor(s, m, 64);
    const float mean = s * (1.0f / 64.0f);
    const float d = acc - mean;
    float q = d * d;
#pragma unroll
    for (int m = 32; m >= 1; m >>= 1) q += __shfl_xor(q, m, 64);
    const float var = q * (1.0f / 64.0f);
    const float xn = d * rsqrtf(var + EPSN) * g1[lane] + be1[lane];
    const float ge = 0.5f * xn * (1.0f + erff(xn * 0.70710678118654752440f));
    xout[row * HID + lane] = ge;
}

// ---------------------------------------------------------------------------
// Kernel 2: GRU scan, wave-specialized, chunk-phased.
//   wave 0: serial scan, h via LDS broadcast.
//   waves 1-2: gi = W_ih.x + b_ih for chunk p (one ahead), double-buffered.
//   wave 3: LN(h@w2+b2) epilogue for chunk p-2, then x prefetch for p+1.
//
// KEY CHANGE vs previous version: VGPR_Count=132 across two rounds despite
// ~240 regs of live weights proves the compiler REMATERIALIZES the
// loop-invariant weight loads (re-issues ~48 global_load_dwordx4 per
// timestep on the critical scan wave, ~200cy L2 latency each batch)
// instead of keeping them resident. Named variables didn't stop it —
// the values are still recomputable-by-reload. Fix: pipe every weight
// register through an opaque  asm volatile("" : "+v"(x))  after init.
// The asm result cannot be rematerialized, so the allocator must keep
// it live; with waves_per_eu(1,1) the per-wave budget is the full
// unified file (VGPR+AGPR), so ~240 live regs fit without spilling.
//   wave 0: A=W_hh r-rows, B=z-rows, C=n-rows
//   wave 1: A=W_ih r-rows, B=W_ih n-rows
//   wave 2: A=W_ih z-rows
//   wave 3: A=w2 column (lane's output dim)
// ---------------------------------------------------------------------------
__global__ __launch_bounds__(256, 1)
__attribute__((amdgpu_waves_per_eu(1, 1)))
void k_gru(float* xo,
           const float* __restrict__ W_ih, const float* __restrict__ b_ih,
           const float* __restrict__ W_hh, const float* __restrict__ b_hh,
           const float* __restrict__ w2, const float* __restrict__ b2,
           const float* __restrict__ g2, const float* __restrict__ be2) {
    __shared__ __align__(16) float4 xbuf[2][CH][16];    // 8 KB  x chunks
    __shared__ __align__(16) float gibuf[2][CH][192];   // 24 KB gi preacts
    __shared__ __align__(16) float hist[2][CH][HID];    // 8 KB  h history
    __shared__ __align__(16) float hbuf[HID];           // h broadcast (wave 0)

    const int tid = threadIdx.x;
    const int lane = tid & 63;
    const int wv = tid >> 6;
    float* xb = xo + (size_t)blockIdx.x * TST * HID;

#define DECLW(i) v2f A##i = {0.f, 0.f}, B##i = {0.f, 0.f}, C##i = {0.f, 0.f};
    REP32(DECLW)
    float sc0 = 0.f, sc1 = 0.f, sc2 = 0.f;   // per-wave scalar params

    if (wv == 0) {
        const v2f* r0 = (const v2f*)(W_hh + (size_t)lane * HID);
        const v2f* r1 = (const v2f*)(W_hh + (size_t)(64 + lane) * HID);
        const v2f* r2 = (const v2f*)(W_hh + (size_t)(128 + lane) * HID);
#define LW0(i) A##i = r0[i]; B##i = r1[i]; C##i = r2[i];
        REP32(LW0)
        sc0 = b_hh[lane]; sc1 = b_hh[64 + lane]; sc2 = b_hh[128 + lane];
        hbuf[lane] = 0.0f;
    } else if (wv == 1) {
        const v2f* rA = (const v2f*)(W_ih + (size_t)lane * HID);
        const v2f* rB = (const v2f*)(W_ih + (size_t)(128 + lane) * HID);
#define LW1(i) A##i = rA[i]; B##i = rB[i];
        REP32(LW1)
        sc0 = b_ih[lane]; sc1 = b_ih[128 + lane];
    } else if (wv == 2) {
        const v2f* rC = (const v2f*)(W_ih + (size_t)(64 + lane) * HID);
#define LW2(i) A##i = rC[i];
        REP32(LW2)
        sc0 = b_ih[64 + lane];
    } else {
#define LW3(i) A##i.x = w2[(size_t)(2 * (i)) * HID + lane]; \
               A##i.y = w2[(size_t)(2 * (i) + 1) * HID + lane];
        REP32(LW3)
        sc0 = b2[lane]; sc1 = g2[lane]; sc2 = be2[lane];
    }

    // Opaque pin: values become non-rematerializable -> must stay in regs.
#define PINW(i) asm volatile("" : "+v"(A##i), "+v"(B##i), "+v"(C##i));
    REP32(PINW)

    {
        const float4* src = (const float4*)xb;
        ((float4*)xbuf[0])[tid] = src[tid];
    }
    float h_reg = 0.0f;
    __syncthreads();

    for (int p = 0; p <= NCH + 1; ++p) {
        if (wv == 0) {
            if (p >= 1 && p <= NCH) {
                const int c = p - 1;
                const float* gp = (const float*)gibuf[c & 1];
                float* hp = (float*)hist[c & 1];
                for (int t = 0; t < CH; ++t) {
                    const float gr = gp[t * 192 + lane];
                    const float gz = gp[t * 192 + 64 + lane];
                    const float gn = gp[t * 192 + 128 + lane];
                    const v2f* hv = (const v2f*)hbuf;
                    // 2-way split accumulators: halve the dependent FMA chain
                    v2f ar0 = {0.f, 0.f}, ar1 = {0.f, 0.f};
                    v2f az0 = {0.f, 0.f}, az1 = {0.f, 0.f};
                    v2f an0 = {0.f, 0.f}, an1 = {0.f, 0.f};
#define SFMA(i) { const v2f h2 = hv[i]; \
                  if ((i) & 1) { ar1 += A##i * h2; az1 += B##i * h2; an1 += C##i * h2; } \
                  else         { ar0 += A##i * h2; az0 += B##i * h2; an0 += C##i * h2; } }
                    REP32(SFMA)
                    const v2f arv = ar0 + ar1;
                    const v2f azv = az0 + az1;
                    const v2f anv = an0 + an1;
                    const float rpre = gr + arv.x + arv.y + sc0;
                    const float zpre = gz + azv.x + azv.y + sc1;
                    const float hn = anv.x + anv.y + sc2;
                    const float r = 1.0f / (1.0f + __expf(-rpre));
                    const float z = 1.0f / (1.0f + __expf(-zpre));
                    const float pre = gn + r * hn;
                    const float e2 = __expf(2.0f * pre);
                    const float n = 1.0f - 2.0f / (e2 + 1.0f);
                    h_reg = (1.0f - z) * n + z * h_reg;
                    hbuf[lane] = h_reg;
                    hp[t * HID + lane] = h_reg;
                }
            }
        } else if (wv == 1 || wv == 2) {
            if (p < NCH) {
                const float4* xc = (const float4*)xbuf[p & 1];
                float* gp = (float*)gibuf[p & 1];
                for (int t = 0; t < CH; ++t) {
                    const v2f* xv = (const v2f*)(xc + t * 16);
                    v2f aA0 = {0.f, 0.f}, aA1 = {0.f, 0.f};
                    v2f aB0 = {0.f, 0.f}, aB1 = {0.f, 0.f};
                    if (wv == 1) {
#define GFMA1(i) { const v2f x2 = xv[i]; \
                   if ((i) & 1) { aA1 += A##i * x2; aB1 += B##i * x2; } \
                   else         { aA0 += A##i * x2; aB0 += B##i * x2; } }
                        REP32(GFMA1)
                        gp[t * 192 + lane] = aA0.x + aA0.y + aA1.x + aA1.y + sc0;
                        gp[t * 192 + 128 + lane] = aB0.x + aB0.y + aB1.x + aB1.y + sc1;
                    } else {
#define GFMA2(i) { const v2f x2 = xv[i]; \
                   if ((i) & 1) { aA1 += A##i * x2; } \
                   else         { aA0 += A##i * x2; } }
                        REP32(GFMA2)
                        gp[t * 192 + 64 + lane] = aA0.x + aA0.y + aA1.x + aA1.y + sc0;
                    }
                }
            }
        } else {
            // ---- epilogue for chunk p-2: LN over 16 timesteps, 2 halves of 8 ----
            if (p >= 2) {
                const int ce = p - 2;
                const float* hp = (const float*)hist[ce & 1];
#pragma unroll
                for (int half = 0; half < 2; ++half) {
                    float yv[8], sv[8], qv[8];
#pragma unroll
                    for (int u = 0; u < 8; ++u) {
                        const int t = half * 8 + u;
                        const v2f* hr = (const v2f*)(hp + t * HID);
                        v2f a20 = {0.f, 0.f}, a21 = {0.f, 0.f};
#define EFMA(i) { const v2f h2 = hr[i]; \
                  if ((i) & 1) { a21 += A##i * h2; } else { a20 += A##i * h2; } }
                        REP32(EFMA)
                        yv[u] = sc0 + a20.x + a20.y + a21.x + a21.y;
                    }
#pragma unroll
                    for (int u = 0; u < 8; ++u) { sv[u] = yv[u]; qv[u] = yv[u] * yv[u]; }
                    // 16 independent shuffle streams per level -> latency overlaps
#pragma unroll
                    for (int m = 32; m >= 1; m >>= 1) {
#pragma unroll
                        for (int u = 0; u < 8; ++u) sv[u] += __shfl_xor(sv[u], m, 64);
#pragma unroll
                        for (int u = 0; u < 8; ++u) qv[u] += __shfl_xor(qv[u], m, 64);
                    }
#pragma unroll
                    for (int u = 0; u < 8; ++u) {
                        const int t = half * 8 + u;
                        const float mean = sv[u] * (1.0f / 64.0f);
                        const float var = qv[u] * (1.0f / 64.0f) - mean * mean;
                        const float dd = yv[u] - mean;
                        xb[(size_t)(ce * CH + t) * HID + lane] =
                            dd * rsqrtf(var + EPSN) * sc1 + sc2;
                    }
                }
            }
            // prefetch x chunk p+1
            if (p + 1 < NCH) {
                const float4* src = (const float4*)(xb + (size_t)(p + 1) * CH * HID);
                float4* dst = (float4*)xbuf[(p + 1) & 1];
#pragma unroll
                for (int q2 = 0; q2 < 4; ++q2) dst[lane + q2 * 64] = src[lane + q2 * 64];
            }
        }
        __syncthreads();
    }
}

extern "C" void kernel_launch(void* const* d_in, const int* in_sizes, int n_in,
                              void* d_out, int out_size, void* d_ws, size_t ws_size,
                              hipStream_t stream) {
    const float* ce  = (const float*)d_in[0];
    const float* w1  = (const float*)d_in[1];
    const float* b1  = (const float*)d_in[2];
    const float* g1  = (const float*)d_in[3];
    const float* be1 = (const float*)d_in[4];
    const float* Wih = (const float*)d_in[5];
    const float* bih = (const float*)d_in[6];
    const float* Whh = (const float*)d_in[7];
    const float* bhh = (const float*)d_in[8];
    const float* w2  = (const float*)d_in[9];
    const float* b2  = (const float*)d_in[10];
    const float* g2  = (const float*)d_in[11];
    const float* be2 = (const float*)d_in[12];
    float* out = (float*)d_out;

    const int nrows = in_sizes[0] / 6;   // B*T
    const int B = nrows / TST;           // 256

    k_inproj<<<(nrows + 3) / 4, 256, 0, stream>>>(ce, w1, b1, g1, be1, out, nrows);
    k_gru<<<B, 256, 0, stream>>>(out, Wih, bih, Whh, bhh, w2, b2, g2, be2);
}

// Round 4
// 1785.297 us; speedup vs baseline: 1.1200x; 1.0095x over previous
//
#include <hip/hip_runtime.h>
#include <math.h>

#define HID 64
#define TST 2048
#define CH 16              // timesteps per chunk
#define NCH (TST / CH)     // 128 chunks
#define EPSN 1e-5f

typedef float v2f __attribute__((ext_vector_type(2)));

#define REP32(M) M(0) M(1) M(2) M(3) M(4) M(5) M(6) M(7) \
                 M(8) M(9) M(10) M(11) M(12) M(13) M(14) M(15) \
                 M(16) M(17) M(18) M(19) M(20) M(21) M(22) M(23) \
                 M(24) M(25) M(26) M(27) M(28) M(29) M(30) M(31)

// ---------------------------------------------------------------------------
// Kernel 1: x = GELU(LayerNorm(ce @ w1 + b1))  -> staged into d_out (unchanged)
// ---------------------------------------------------------------------------
__global__ void k_inproj(const float* __restrict__ ce, const float* __restrict__ w1,
                         const float* __restrict__ b1, const float* __restrict__ g1,
                         const float* __restrict__ be1, float* __restrict__ xout,
                         int nrows) {
    const int lane = threadIdx.x & 63;
    const int wave = threadIdx.x >> 6;
    const long row = (long)blockIdx.x * 4 + wave;
    if (row >= nrows) return;
    const float* cr = ce + row * 6;
    float acc = b1[lane];
    acc += cr[0] * w1[0 * HID + lane];
    acc += cr[1] * w1[1 * HID + lane];
    acc += cr[2] * w1[2 * HID + lane];
    acc += cr[3] * w1[3 * HID + lane];
    acc += cr[4] * w1[4 * HID + lane];
    acc += cr[5] * w1[5 * HID + lane];
    float s = acc;
#pragma unroll
    for (int m = 32; m >= 1; m >>= 1) s += __shfl_xor(s, m, 64);
    const float mean = s * (1.0f / 64.0f);
    const float d = acc - mean;
    float q = d * d;
#pragma unroll
    for (int m = 32; m >= 1; m >>= 1) q += __shfl_xor(q, m, 64);
    const float var = q * (1.0f / 64.0f);
    const float xn = d * rsqrtf(var + EPSN) * g1[lane] + be1[lane];
    const float ge = 0.5f * xn * (1.0f + erff(xn * 0.70710678118654752440f));
    xout[row * HID + lane] = ge;
}

// Identical GRU combine for every wave that tracks h (bitwise-deterministic).
__device__ __forceinline__ float gru_step(float gr, float gz, float gn,
                                          float pr, float pz, float pn, float h) {
    const float r = 1.0f / (1.0f + __expf(-(gr + pr)));
    const float z = 1.0f / (1.0f + __expf(-(gz + pz)));
    const float pre = gn + r * pn;
    const float e2 = __expf(2.0f * pre);
    const float n = 1.0f - 2.0f / (e2 + 1.0f);
    return (1.0f - z) * n + z * h;
}

// ---------------------------------------------------------------------------
// Kernel 2: GRU scan, 8 waves, ONE gate per wave (64 weight VGPRs per wave —
// the size the allocator demonstrably keeps resident; 192-reg sets get
// rematerialized from L2 every step, ~50 GB of L2 traffic = the old 1.6 ms).
//   waves 0-2: W_hh gate g rows. Per step: redundant combine (h lane-local),
//              private LDS h-broadcast (intra-wave), 32 pk_fma matvec,
//              partial -> double-buffered part[].
//   waves 3-5: W_ih gate g rows. gi for step s+16 -> gibuf (double-buffered).
//   wave 6:    w2 column. LN epilogue on quad-buffered hist, y staged in LDS
//              (avoids runtime-indexed reg arrays), 4-row reduce slices.
//   wave 7:    4th redundant combine -> hist writes; batched x prefetch
//              (chunk c+2) once per chunk at t==0.
// One __syncthreads per timestep paces all cross-wave handoffs.
// ---------------------------------------------------------------------------
__global__ __launch_bounds__(512, 2)
void k_gru(float* xo,
           const float* __restrict__ W_ih, const float* __restrict__ b_ih,
           const float* __restrict__ W_hh, const float* __restrict__ b_hh,
           const float* __restrict__ w2, const float* __restrict__ b2,
           const float* __restrict__ g2, const float* __restrict__ be2) {
    __shared__ __align__(16) float4 xbuf[2][CH][16];    // 8 KB   x chunks
    __shared__ __align__(16) float gibuf[2][CH][192];   // 24 KB  gi preacts
    __shared__ __align__(16) float hist[4][CH][HID];    // 16 KB  h history (quad)
    __shared__ __align__(16) float hb[3][HID];          // 768 B  per-scan-wave h bcast
    __shared__ __align__(16) float part[2][3][HID];     // 1.5 KB gate partials (dbuf)
    __shared__ __align__(16) float ybuf[2][8][HID];     // 4 KB   epilogue y staging

    const int tid = threadIdx.x;
    const int lane = tid & 63;
    const int wv = tid >> 6;
    float* xb = xo + (size_t)blockIdx.x * TST * HID;

#define DECLW(i) v2f W##i = {0.f, 0.f};
    REP32(DECLW)
    float bh = 0.f, b2r = 0.f, g2r = 0.f, be2r = 0.f;

    if (wv < 6) {
        const float* wbp = (wv < 3) ? (W_hh + (size_t)(wv * 64 + lane) * HID)
                                    : (W_ih + (size_t)((wv - 3) * 64 + lane) * HID);
        const v2f* r0 = (const v2f*)wbp;
#define LWR(i) W##i = r0[i];
        REP32(LWR)
        bh = (wv < 3) ? b_hh[wv * 64 + lane] : b_ih[(wv - 3) * 64 + lane];
    } else if (wv == 6) {
#define LW6(i) W##i.x = w2[(size_t)(2 * (i)) * HID + lane]; \
               W##i.y = w2[(size_t)(2 * (i) + 1) * HID + lane];
        REP32(LW6)
        b2r = b2[lane]; g2r = g2[lane]; be2r = be2[lane];
    }
#define PINW(i) asm volatile("" : "+v"(W##i));
    REP32(PINW)

    // Prefill: x chunk 0, initial partials (W·h(-1)+b = b), h0 = 0.
    if (tid < 256) ((float4*)&xbuf[0][0][0])[tid] = ((const float4*)xb)[tid];
    if (wv < 3) part[0][wv][lane] = bh;
    float h_reg = 0.f;
    float pown = bh;   // scan wave's own-gate partial (register copy of part[])
    __syncthreads();

#define MACH(i) { const v2f u = hv[i]; if ((i) & 1) a1 += W##i * u; else a0 += W##i * u; }
#define MACX(i) { const v2f u = xv[i]; if ((i) & 1) a1 += W##i * u; else a0 += W##i * u; }
#define MACE(i) { const v2f u = hr[i]; if ((i) & 1) a1 += W##i * u; else a0 += W##i * u; }

#define LNR4(slot, ub, chk, rbase) { \
    float yv[4], sv[4], qv[4]; \
    _Pragma("unroll") for (int u = 0; u < 4; ++u) yv[u] = ybuf[slot][(ub) + u][lane]; \
    _Pragma("unroll") for (int u = 0; u < 4; ++u) { sv[u] = yv[u]; qv[u] = yv[u] * yv[u]; } \
    _Pragma("unroll") for (int m = 32; m >= 1; m >>= 1) { \
        _Pragma("unroll") for (int u = 0; u < 4; ++u) sv[u] += __shfl_xor(sv[u], m, 64); \
        _Pragma("unroll") for (int u = 0; u < 4; ++u) qv[u] += __shfl_xor(qv[u], m, 64); } \
    _Pragma("unroll") for (int u = 0; u < 4; ++u) { \
        const float mean = sv[u] * (1.0f / 64.0f); \
        const float var = qv[u] * (1.0f / 64.0f) - mean * mean; \
        const float dd = yv[u] - mean; \
        xb[(size_t)((chk) * CH + (rbase) + u) * HID + lane] = \
            dd * rsqrtf(var + EPSN) * g2r + be2r; } }

    for (int s = -16; s <= 2081; ++s) {
        const int c = s >> 4;      // arithmetic shift: correct for s<0
        const int t = s & 15;
        if (wv < 3) {
            // ---- scan gate wv: combine + matvec for step s ----
            if (s >= 0 && s < TST) {
                const float* gp = &gibuf[c & 1][t][0];
                const float gr = gp[lane], gz = gp[64 + lane], gn = gp[128 + lane];
                float pr, pz, pn;
                if (wv == 0)      { pr = pown;                   pz = part[s & 1][1][lane]; pn = part[s & 1][2][lane]; }
                else if (wv == 1) { pr = part[s & 1][0][lane];   pz = pown;                 pn = part[s & 1][2][lane]; }
                else              { pr = part[s & 1][0][lane];   pz = part[s & 1][1][lane]; pn = pown; }
                h_reg = gru_step(gr, gz, gn, pr, pz, pn, h_reg);
                hb[wv][lane] = h_reg;                       // intra-wave broadcast
                const v2f* hv = (const v2f*)&hb[wv][0];
                v2f a0 = {0.f, 0.f}, a1 = {0.f, 0.f};
                REP32(MACH)
                const v2f av = a0 + a1;
                pown = av.x + av.y + bh;                    // partial for step s+1
                part[(s + 1) & 1][wv][lane] = pown;
            }
        } else if (wv < 6) {
            // ---- gi gate (wv-3) for step s+16 ----
            if (s < TST - CH) {
                const int sf = s + CH;
                const v2f* xv = (const v2f*)&xbuf[(sf >> 4) & 1][sf & 15][0];
                v2f a0 = {0.f, 0.f}, a1 = {0.f, 0.f};
                REP32(MACX)
                const v2f av = a0 + a1;
                gibuf[(sf >> 4) & 1][sf & 15][(wv - 3) * 64 + lane] = av.x + av.y + bh;
            }
        } else if (wv == 6) {
            // ---- epilogue: y-dot row t of chunk c-2; 4-row reduce slices ----
            if (s >= 32 && c <= 129) {
                const v2f* hr = (const v2f*)&hist[(c - 2) & 3][t][0];
                v2f a0 = {0.f, 0.f}, a1 = {0.f, 0.f};
                REP32(MACE)
                const v2f av = a0 + a1;
                ybuf[t >> 3][t & 7][lane] = b2r + av.x + av.y;
            }
            if ((t == 8 || t == 9) && c >= 2 && c <= 129) {
                const int ub = (t - 8) * 4;
                LNR4(0, ub, c - 2, ub)              // rows 0-3 / 4-7 of chunk c-2
            }
            if ((t == 0 || t == 1) && c >= 3 && c <= 130) {
                const int ub = t * 4;
                LNR4(1, ub, c - 3, 8 + ub)          // rows 8-11 / 12-15 of chunk c-3
            }
        } else {
            // ---- wave 7: 4th combine -> hist; batched x prefetch ----
            if (s >= 0 && s < TST) {
                const float* gp = &gibuf[c & 1][t][0];
                const float pr = part[s & 1][0][lane];
                const float pz = part[s & 1][1][lane];
                const float pn = part[s & 1][2][lane];
                h_reg = gru_step(gp[lane], gp[64 + lane], gp[128 + lane], pr, pz, pn, h_reg);
                hist[c & 3][t][lane] = h_reg;
            }
            if (t == 0 && c >= -1 && c <= 125) {
                // prefetch x chunk c+2 into xbuf slot (c+2)&1 == c&1
                const float4* src = (const float4*)(xb + (size_t)(c + 2) * CH * HID);
                float4* dst = (float4*)&xbuf[c & 1][0][0];
#pragma unroll
                for (int q = 0; q < 4; ++q) dst[lane + q * 64] = src[lane + q * 64];
            }
        }
        __syncthreads();
    }
}

extern "C" void kernel_launch(void* const* d_in, const int* in_sizes, int n_in,
                              void* d_out, int out_size, void* d_ws, size_t ws_size,
                              hipStream_t stream) {
    const float* ce  = (const float*)d_in[0];
    const float* w1  = (const float*)d_in[1];
    const float* b1  = (const float*)d_in[2];
    const float* g1  = (const float*)d_in[3];
    const float* be1 = (const float*)d_in[4];
    const float* Wih = (const float*)d_in[5];
    const float* bih = (const float*)d_in[6];
    const float* Whh = (const float*)d_in[7];
    const float* bhh = (const float*)d_in[8];
    const float* w2  = (const float*)d_in[9];
    const float* b2  = (const float*)d_in[10];
    const float* g2  = (const float*)d_in[11];
    const float* be2 = (const float*)d_in[12];
    float* out = (float*)d_out;

    const int nrows = in_sizes[0] / 6;   // B*T
    const int B = nrows / TST;           // 256

    k_inproj<<<(nrows + 3) / 4, 256, 0, stream>>>(ce, w1, b1, g1, be1, out, nrows);
    k_gru<<<B, 512, 0, stream>>>(out, Wih, bih, Whh, bhh, w2, b2, g2, be2);
}

// Round 5
// 1725.263 us; speedup vs baseline: 1.1590x; 1.0348x over previous
//
#include <hip/hip_runtime.h>
#include <math.h>

#define HID 64
#define TST 2048
#define CH 16              // timesteps per chunk
#define NCH (TST / CH)     // 128 chunks
#define EPSN 1e-5f

typedef float v2f __attribute__((ext_vector_type(2)));

#define REP32(M) M(0) M(1) M(2) M(3) M(4) M(5) M(6) M(7) \
                 M(8) M(9) M(10) M(11) M(12) M(13) M(14) M(15) \
                 M(16) M(17) M(18) M(19) M(20) M(21) M(22) M(23) \
                 M(24) M(25) M(26) M(27) M(28) M(29) M(30) M(31)

// ---------------------------------------------------------------------------
// Kernel 1: x = GELU(LayerNorm(ce @ w1 + b1))  -> staged into d_out (unchanged)
// ---------------------------------------------------------------------------
__global__ void k_inproj(const float* __restrict__ ce, const float* __restrict__ w1,
                         const float* __restrict__ b1, const float* __restrict__ g1,
                         const float* __restrict__ be1, float* __restrict__ xout,
                         int nrows) {
    const int lane = threadIdx.x & 63;
    const int wave = threadIdx.x >> 6;
    const long row = (long)blockIdx.x * 4 + wave;
    if (row >= nrows) return;
    const float* cr = ce + row * 6;
    float acc = b1[lane];
    acc += cr[0] * w1[0 * HID + lane];
    acc += cr[1] * w1[1 * HID + lane];
    acc += cr[2] * w1[2 * HID + lane];
    acc += cr[3] * w1[3 * HID + lane];
    acc += cr[4] * w1[4 * HID + lane];
    acc += cr[5] * w1[5 * HID + lane];
    float s = acc;
#pragma unroll
    for (int m = 32; m >= 1; m >>= 1) s += __shfl_xor(s, m, 64);
    const float mean = s * (1.0f / 64.0f);
    const float d = acc - mean;
    float q = d * d;
#pragma unroll
    for (int m = 32; m >= 1; m >>= 1) q += __shfl_xor(q, m, 64);
    const float var = q * (1.0f / 64.0f);
    const float xn = d * rsqrtf(var + EPSN) * g1[lane] + be1[lane];
    const float ge = 0.5f * xn * (1.0f + erff(xn * 0.70710678118654752440f));
    xout[row * HID + lane] = ge;
}

// Identical GRU combine for every wave that tracks h (bitwise-deterministic).
__device__ __forceinline__ float gru_step(float gr, float gz, float gn,
                                          float pr, float pz, float pn, float h) {
    const float r = 1.0f / (1.0f + __expf(-(gr + pr)));
    const float z = 1.0f / (1.0f + __expf(-(gz + pz)));
    const float pre = gn + r * pn;
    const float e2 = __expf(2.0f * pre);
    const float n = 1.0f - 2.0f / (e2 + 1.0f);
    return (1.0f - z) * n + z * h;
}

// ---------------------------------------------------------------------------
// Kernel 2: GRU scan, 8 waves, one gate per wave.
//
// KEY CHANGE vs R4: weights pinned into AGPRs via asm "+a" constraint.
// Evidence trail: R1-R4 all land at ~1640us (1878 cy/step) with VGPR_Count
// far below the weight working set -> the allocator spills/remats the
// weight registers through L2 every step. Traffic model closes exactly:
// 7 waves x 16KB/step = 112KB/step/CU at ~56 B/cy per-CU L2 bandwidth
// = 2000 cy/step ~= measured 1878. "+v" pins failed because RA can still
// spill pinned values to scratch (same L2 path). AGPRs are the fix: the
// "a" constraint forces the value into the accumulation file (gfx950
// unified RF); access is a 1-cy v_accvgpr_read register move, and there
// is no memory path — spill/remat of a register move stays in registers.
//   waves 0-2: W_hh gate rows (64 AGPRs each) — redundant combine + matvec.
//   waves 3-5: W_ih gate rows — gi for step s+16 -> gibuf.
//   wave 6:    w2 column — LN epilogue on quad-buffered hist.
//   wave 7:    4th redundant combine -> hist; batched x prefetch.
// One __syncthreads per timestep paces all cross-wave handoffs.
// ---------------------------------------------------------------------------
__global__ __launch_bounds__(512, 2)
void k_gru(float* xo,
           const float* __restrict__ W_ih, const float* __restrict__ b_ih,
           const float* __restrict__ W_hh, const float* __restrict__ b_hh,
           const float* __restrict__ w2, const float* __restrict__ b2,
           const float* __restrict__ g2, const float* __restrict__ be2) {
    __shared__ __align__(16) float4 xbuf[2][CH][16];    // 8 KB   x chunks
    __shared__ __align__(16) float gibuf[2][CH][192];   // 24 KB  gi preacts
    __shared__ __align__(16) float hist[4][CH][HID];    // 16 KB  h history (quad)
    __shared__ __align__(16) float hb[3][HID];          // 768 B  per-scan-wave h bcast
    __shared__ __align__(16) float part[2][3][HID];     // 1.5 KB gate partials (dbuf)
    __shared__ __align__(16) float ybuf[2][8][HID];     // 4 KB   epilogue y staging

    const int tid = threadIdx.x;
    const int lane = tid & 63;
    const int wv = tid >> 6;
    float* xb = xo + (size_t)blockIdx.x * TST * HID;

#define DECLW(i) v2f W##i = {0.f, 0.f};
    REP32(DECLW)
    float bh = 0.f, b2r = 0.f, g2r = 0.f, be2r = 0.f;

    if (wv < 6) {
        const float* wbp = (wv < 3) ? (W_hh + (size_t)(wv * 64 + lane) * HID)
                                    : (W_ih + (size_t)((wv - 3) * 64 + lane) * HID);
        const v2f* r0 = (const v2f*)wbp;
#define LWR(i) W##i = r0[i];
        REP32(LWR)
        bh = (wv < 3) ? b_hh[wv * 64 + lane] : b_ih[(wv - 3) * 64 + lane];
    } else if (wv == 6) {
#define LW6(i) W##i.x = w2[(size_t)(2 * (i)) * HID + lane]; \
               W##i.y = w2[(size_t)(2 * (i) + 1) * HID + lane];
        REP32(LW6)
        b2r = b2[lane]; g2r = g2[lane]; be2r = be2[lane];
    }
    // Park every weight pair in the AGPR file: no memory path to/from here.
#define PINW(i) asm volatile("" : "+a"(W##i));
    REP32(PINW)

    // Prefill: x chunk 0, initial partials (W·h(-1)+b = b), h0 = 0.
    if (tid < 256) ((float4*)&xbuf[0][0][0])[tid] = ((const float4*)xb)[tid];
    if (wv < 3) part[0][wv][lane] = bh;
    float h_reg = 0.f;
    float pown = bh;   // scan wave's own-gate partial (register copy of part[])
    __syncthreads();

#define MACH(i) { const v2f u = hv[i]; if ((i) & 1) a1 += W##i * u; else a0 += W##i * u; }
#define MACX(i) { const v2f u = xv[i]; if ((i) & 1) a1 += W##i * u; else a0 += W##i * u; }
#define MACE(i) { const v2f u = hr[i]; if ((i) & 1) a1 += W##i * u; else a0 += W##i * u; }

#define LNR4(slot, ub, chk, rbase) { \
    float yv[4], sv[4], qv[4]; \
    _Pragma("unroll") for (int u = 0; u < 4; ++u) yv[u] = ybuf[slot][(ub) + u][lane]; \
    _Pragma("unroll") for (int u = 0; u < 4; ++u) { sv[u] = yv[u]; qv[u] = yv[u] * yv[u]; } \
    _Pragma("unroll") for (int m = 32; m >= 1; m >>= 1) { \
        _Pragma("unroll") for (int u = 0; u < 4; ++u) sv[u] += __shfl_xor(sv[u], m, 64); \
        _Pragma("unroll") for (int u = 0; u < 4; ++u) qv[u] += __shfl_xor(qv[u], m, 64); } \
    _Pragma("unroll") for (int u = 0; u < 4; ++u) { \
        const float mean = sv[u] * (1.0f / 64.0f); \
        const float var = qv[u] * (1.0f / 64.0f) - mean * mean; \
        const float dd = yv[u] - mean; \
        xb[(size_t)((chk) * CH + (rbase) + u) * HID + lane] = \
            dd * rsqrtf(var + EPSN) * g2r + be2r; } }

    for (int s = -16; s <= 2081; ++s) {
        const int c = s >> 4;      // arithmetic shift: correct for s<0
        const int t = s & 15;
        if (wv < 3) {
            // ---- scan gate wv: combine + matvec for step s ----
            if (s >= 0 && s < TST) {
                const float* gp = &gibuf[c & 1][t][0];
                const float gr = gp[lane], gz = gp[64 + lane], gn = gp[128 + lane];
                float pr, pz, pn;
                if (wv == 0)      { pr = pown;                   pz = part[s & 1][1][lane]; pn = part[s & 1][2][lane]; }
                else if (wv == 1) { pr = part[s & 1][0][lane];   pz = pown;                 pn = part[s & 1][2][lane]; }
                else              { pr = part[s & 1][0][lane];   pz = part[s & 1][1][lane]; pn = pown; }
                h_reg = gru_step(gr, gz, gn, pr, pz, pn, h_reg);
                hb[wv][lane] = h_reg;                       // intra-wave broadcast
                const v2f* hv = (const v2f*)&hb[wv][0];
                v2f a0 = {0.f, 0.f}, a1 = {0.f, 0.f};
                REP32(MACH)
                const v2f av = a0 + a1;
                pown = av.x + av.y + bh;                    // partial for step s+1
                part[(s + 1) & 1][wv][lane] = pown;
            }
        } else if (wv < 6) {
            // ---- gi gate (wv-3) for step s+16 ----
            if (s < TST - CH) {
                const int sf = s + CH;
                const v2f* xv = (const v2f*)&xbuf[(sf >> 4) & 1][sf & 15][0];
                v2f a0 = {0.f, 0.f}, a1 = {0.f, 0.f};
                REP32(MACX)
                const v2f av = a0 + a1;
                gibuf[(sf >> 4) & 1][sf & 15][(wv - 3) * 64 + lane] = av.x + av.y + bh;
            }
        } else if (wv == 6) {
            // ---- epilogue: y-dot row t of chunk c-2; 4-row reduce slices ----
            if (s >= 32 && c <= 129) {
                const v2f* hr = (const v2f*)&hist[(c - 2) & 3][t][0];
                v2f a0 = {0.f, 0.f}, a1 = {0.f, 0.f};
                REP32(MACE)
                const v2f av = a0 + a1;
                ybuf[t >> 3][t & 7][lane] = b2r + av.x + av.y;
            }
            if ((t == 8 || t == 9) && c >= 2 && c <= 129) {
                const int ub = (t - 8) * 4;
                LNR4(0, ub, c - 2, ub)              // rows 0-3 / 4-7 of chunk c-2
            }
            if ((t == 0 || t == 1) && c >= 3 && c <= 130) {
                const int ub = t * 4;
                LNR4(1, ub, c - 3, 8 + ub)          // rows 8-11 / 12-15 of chunk c-3
            }
        } else {
            // ---- wave 7: 4th combine -> hist; batched x prefetch ----
            if (s >= 0 && s < TST) {
                const float* gp = &gibuf[c & 1][t][0];
                const float pr = part[s & 1][0][lane];
                const float pz = part[s & 1][1][lane];
                const float pn = part[s & 1][2][lane];
                h_reg = gru_step(gp[lane], gp[64 + lane], gp[128 + lane], pr, pz, pn, h_reg);
                hist[c & 3][t][lane] = h_reg;
            }
            if (t == 0 && c >= -1 && c <= 125) {
                // prefetch x chunk c+2 into xbuf slot (c+2)&1 == c&1
                const float4* src = (const float4*)(xb + (size_t)(c + 2) * CH * HID);
                float4* dst = (float4*)&xbuf[c & 1][0][0];
#pragma unroll
                for (int q = 0; q < 4; ++q) dst[lane + q * 64] = src[lane + q * 64];
            }
        }
        __syncthreads();
    }
}

extern "C" void kernel_launch(void* const* d_in, const int* in_sizes, int n_in,
                              void* d_out, int out_size, void* d_ws, size_t ws_size,
                              hipStream_t stream) {
    const float* ce  = (const float*)d_in[0];
    const float* w1  = (const float*)d_in[1];
    const float* b1  = (const float*)d_in[2];
    const float* g1  = (const float*)d_in[3];
    const float* be1 = (const float*)d_in[4];
    const float* Wih = (const float*)d_in[5];
    const float* bih = (const float*)d_in[6];
    const float* Whh = (const float*)d_in[7];
    const float* bhh = (const float*)d_in[8];
    const float* w2  = (const float*)d_in[9];
    const float* b2  = (const float*)d_in[10];
    const float* g2  = (const float*)d_in[11];
    const float* be2 = (const float*)d_in[12];
    float* out = (float*)d_out;

    const int nrows = in_sizes[0] / 6;   // B*T
    const int B = nrows / TST;           // 256

    k_inproj<<<(nrows + 3) / 4, 256, 0, stream>>>(ce, w1, b1, g1, be1, out, nrows);
    k_gru<<<B, 512, 0, stream>>>(out, Wih, bih, Whh, bhh, w2, b2, g2, be2);
}